// Round 1
// baseline (196.410 us; speedup 1.0000x reference)
//
#include <hip/hip_runtime.h>

// SatelliteImageGNN: 3-layer GCN on a 768x768 8-neighbor grid + pixel shuffle.
// Key identity: GCN layer = dinv * boxsum3x3(dinv .* h) @ W + b  (boxsum commutes
// with the per-node matmul), dinv derived from position (no edge_index needed).
// Fully fused single kernel: per-block 16x16 output tile, halos 22->20->18->16,
// all intermediates in LDS.

constexpr int HH   = 768;
constexpr int SS   = 3;
constexpr int HID  = 32;
constexpr int TILE = 16;
constexpr int NB   = HH / TILE;   // 48 blocks per side
constexpr int R1   = TILE + 6;    // 22
constexpr int R2   = TILE + 4;    // 20
constexpr int R3   = TILE + 2;    // 18
constexpr int ST   = 36;          // float stride per node for 32-ch buffers (16B aligned)
constexpr int NT   = 512;

// LDS layout (floats)
constexpr int A0     = 0;                 // region A: max 400*36 = 14400
constexpr int ASZ    = R2 * R2 * ST;      // 14400
constexpr int B0     = A0 + ASZ;          // region B: max 324*36 = 11664
constexpr int BSZ    = R3 * R3 * ST;      // 11664
constexpr int W1OFF  = B0 + BSZ;          // 26064 : W1 row-major [3][32]
constexpr int W2OFF  = W1OFF + 96;        // 26160 : W2 row-major [32][32]
constexpr int W3TOFF = W2OFF + 1024;      // 27184 : W3 transposed [9][32]
constexpr int B1OFF  = W3TOFF + 288;      // 27472
constexpr int B2OFF  = B1OFF + 32;        // 27504
constexpr int B3OFF  = B2OFF + 32;        // 27536
constexpr int SMEMF  = B3OFF + 12;        // 27548 floats = 110,192 B

__device__ __forceinline__ float dinv_of(int gi, int gj) {
    int e = (1 + (gi > 0) + (gi < HH - 1)) * (1 + (gj > 0) + (gj < HH - 1));
    // e in {4, 6, 9} -> 1/2, 1/sqrt(6), 1/3
    return e == 9 ? 0.33333334f : (e == 6 ? 0.40824829f : 0.5f);
}

__device__ __forceinline__ void fma4(float4& acc, float a, const float4 w) {
    acc.x += a * w.x; acc.y += a * w.y; acc.z += a * w.z; acc.w += a * w.w;
}

__global__ __launch_bounds__(NT) void gnn_fused(
    const float* __restrict__ x,
    const float* __restrict__ W1, const float* __restrict__ b1,
    const float* __restrict__ W2, const float* __restrict__ b2,
    const float* __restrict__ W3, const float* __restrict__ b3,
    float* __restrict__ out)
{
    __shared__ __align__(16) float smem[SMEMF];
    const int tid = threadIdx.x;
    const int bi = blockIdx.x / NB;
    const int bj = blockIdx.x % NB;
    const int oi = bi * TILE, oj = bj * TILE;

    // ---- phase 0: stage weights + g0 = dinv .* x on R1 (stride 4) ----
    for (int i = tid; i < 96;   i += NT) smem[W1OFF + i] = W1[i];
    for (int i = tid; i < 1024; i += NT) smem[W2OFF + i] = W2[i];
    for (int i = tid; i < 288;  i += NT) smem[W3TOFF + (i % 9) * 32 + (i / 9)] = W3[i];
    if (tid < 32) { smem[B1OFF + tid] = b1[tid]; smem[B2OFF + tid] = b2[tid]; }
    if (tid < 9)  { smem[B3OFF + tid] = b3[tid]; }

    for (int n = tid; n < R1 * R1; n += NT) {
        int li = n / R1, lj = n % R1;
        int gi = oi - 3 + li, gj = oj - 3 + lj;
        float v0 = 0.f, v1 = 0.f, v2 = 0.f;
        if (gi >= 0 && gi < HH && gj >= 0 && gj < HH) {
            float d = dinv_of(gi, gj);
            const float* xp = x + 3 * ((size_t)gi * HH + gj);
            v0 = d * xp[0]; v1 = d * xp[1]; v2 = d * xp[2];
        }
        smem[A0 + n * 4 + 0] = v0; smem[A0 + n * 4 + 1] = v1;
        smem[A0 + n * 4 + 2] = v2; smem[A0 + n * 4 + 3] = 0.f;
    }
    __syncthreads();

    // ---- bs1: s0 = boxsum(g0) on R2 (3 ch, stride 4, into B) ----
    for (int n = tid; n < R2 * R2; n += NT) {
        int li = n / R2, lj = n % R2;
        float s0 = 0.f, s1 = 0.f, s2 = 0.f;
        #pragma unroll
        for (int di = 0; di < 3; ++di)
            #pragma unroll
            for (int dj = 0; dj < 3; ++dj) {
                int m = (li + di) * R1 + (lj + dj);
                s0 += smem[A0 + m * 4 + 0];
                s1 += smem[A0 + m * 4 + 1];
                s2 += smem[A0 + m * 4 + 2];
            }
        smem[B0 + n * 4 + 0] = s0; smem[B0 + n * 4 + 1] = s1;
        smem[B0 + n * 4 + 2] = s2; smem[B0 + n * 4 + 3] = 0.f;
    }
    __syncthreads();

    // ---- mm1: g1 = dinv * relu(dinv*(s0@W1)+b1) on R2 (32 ch, stride ST, into A) ----
    for (int item = tid; item < R2 * R2 * 8; item += NT) {
        int n = item >> 3, c4 = item & 7;
        int li = n / R2, lj = n % R2;
        int gi = oi - 2 + li, gj = oj - 2 + lj;
        float4 g = {0.f, 0.f, 0.f, 0.f};
        if (gi >= 0 && gi < HH && gj >= 0 && gj < HH) {
            float d = dinv_of(gi, gj);
            float4 acc = {0.f, 0.f, 0.f, 0.f};
            #pragma unroll
            for (int k = 0; k < 3; ++k) {
                float a = smem[B0 + n * 4 + k];
                float4 w = *(const float4*)&smem[W1OFF + k * 32 + 4 * c4];
                fma4(acc, a, w);
            }
            float4 bb = *(const float4*)&smem[B1OFF + 4 * c4];
            g.x = d * fmaxf(d * acc.x + bb.x, 0.f);
            g.y = d * fmaxf(d * acc.y + bb.y, 0.f);
            g.z = d * fmaxf(d * acc.z + bb.z, 0.f);
            g.w = d * fmaxf(d * acc.w + bb.w, 0.f);
        }
        *(float4*)&smem[A0 + n * ST + 4 * c4] = g;
    }
    __syncthreads();

    // ---- bs2: s1 = boxsum(g1) on R3 (into B, stride ST) ----
    for (int item = tid; item < R3 * R3 * 8; item += NT) {
        int n = item >> 3, c4 = item & 7;
        int li = n / R3, lj = n % R3;
        float4 s = {0.f, 0.f, 0.f, 0.f};
        #pragma unroll
        for (int di = 0; di < 3; ++di)
            #pragma unroll
            for (int dj = 0; dj < 3; ++dj) {
                const float4 v = *(const float4*)&smem[A0 + ((li + di) * R2 + (lj + dj)) * ST + 4 * c4];
                s.x += v.x; s.y += v.y; s.z += v.z; s.w += v.w;
            }
        *(float4*)&smem[B0 + n * ST + 4 * c4] = s;
    }
    __syncthreads();

    // ---- mm2: g2 = dinv * relu(dinv*(s1@W2)+b2) on R3 (into A, stride ST) ----
    for (int item = tid; item < R3 * R3 * 8; item += NT) {
        int n = item >> 3, c4 = item & 7;
        int li = n / R3, lj = n % R3;
        int gi = oi - 1 + li, gj = oj - 1 + lj;
        float4 g = {0.f, 0.f, 0.f, 0.f};
        if (gi >= 0 && gi < HH && gj >= 0 && gj < HH) {
            float d = dinv_of(gi, gj);
            float4 acc = {0.f, 0.f, 0.f, 0.f};
            const float4* brow = (const float4*)&smem[B0 + n * ST];
            #pragma unroll
            for (int k4 = 0; k4 < 8; ++k4) {
                float4 a = brow[k4];
                fma4(acc, a.x, *(const float4*)&smem[W2OFF + (4 * k4 + 0) * 32 + 4 * c4]);
                fma4(acc, a.y, *(const float4*)&smem[W2OFF + (4 * k4 + 1) * 32 + 4 * c4]);
                fma4(acc, a.z, *(const float4*)&smem[W2OFF + (4 * k4 + 2) * 32 + 4 * c4]);
                fma4(acc, a.w, *(const float4*)&smem[W2OFF + (4 * k4 + 3) * 32 + 4 * c4]);
            }
            float4 bb = *(const float4*)&smem[B2OFF + 4 * c4];
            g.x = d * fmaxf(d * acc.x + bb.x, 0.f);
            g.y = d * fmaxf(d * acc.y + bb.y, 0.f);
            g.z = d * fmaxf(d * acc.z + bb.z, 0.f);
            g.w = d * fmaxf(d * acc.w + bb.w, 0.f);
        }
        *(float4*)&smem[A0 + n * ST + 4 * c4] = g;
    }
    __syncthreads();

    // ---- bs3: s2 = boxsum(g2) on TILE (into B, stride ST) ----
    for (int item = tid; item < TILE * TILE * 8; item += NT) {
        int n = item >> 3, c4 = item & 7;
        int li = n / TILE, lj = n % TILE;
        float4 s = {0.f, 0.f, 0.f, 0.f};
        #pragma unroll
        for (int di = 0; di < 3; ++di)
            #pragma unroll
            for (int dj = 0; dj < 3; ++dj) {
                const float4 v = *(const float4*)&smem[A0 + ((li + di) * R3 + (lj + dj)) * ST + 4 * c4];
                s.x += v.x; s.y += v.y; s.z += v.z; s.w += v.w;
            }
        *(float4*)&smem[B0 + n * ST + 4 * c4] = s;
    }
    __syncthreads();

    // ---- mm3: out9 = dinv*(s2@W3)+b3 on TILE -> outbuf in A (stride 12) ----
    if (tid < TILE * TILE) {
        int n = tid;
        int li = n / TILE, lj = n % TILE;
        float d = dinv_of(oi + li, oj + lj);
        float a[32];
        const float4* brow = (const float4*)&smem[B0 + n * ST];
        #pragma unroll
        for (int k4 = 0; k4 < 8; ++k4) {
            float4 v = brow[k4];
            a[4 * k4 + 0] = v.x; a[4 * k4 + 1] = v.y;
            a[4 * k4 + 2] = v.z; a[4 * k4 + 3] = v.w;
        }
        #pragma unroll
        for (int c = 0; c < 9; ++c) {
            float acc = 0.f;
            const float4* wr = (const float4*)&smem[W3TOFF + c * 32];
            #pragma unroll
            for (int k4 = 0; k4 < 8; ++k4) {
                float4 w = wr[k4];
                acc += a[4 * k4 + 0] * w.x + a[4 * k4 + 1] * w.y
                     + a[4 * k4 + 2] * w.z + a[4 * k4 + 3] * w.w;
            }
            smem[A0 + n * 12 + c] = d * acc + smem[B3OFF + c];
        }
    }
    __syncthreads();

    // ---- pixel-shuffle write: rows of 48 consecutive floats per (i,si) ----
    const int or0 = oi * SS, oc0 = oj * SS;
    for (int lin = tid; lin < TILE * TILE * 9; lin += NT) {
        int rr = lin / 48;            // ii*3+si
        int cc = lin % 48;            // jj*3+sj
        int ii = rr / 3, si = rr % 3, jj = cc / 3, sj = cc % 3;
        float v = smem[A0 + (ii * TILE + jj) * 12 + si * 3 + sj];
        out[(size_t)(or0 + rr) * (HH * SS) + oc0 + cc] = v;
    }
}

extern "C" void kernel_launch(void* const* d_in, const int* in_sizes, int n_in,
                              void* d_out, int out_size, void* d_ws, size_t ws_size,
                              hipStream_t stream) {
    const float* x  = (const float*)d_in[0];
    // d_in[1] = edge_index (int32) — structure is a fixed grid; derived analytically.
    const float* W1 = (const float*)d_in[2];
    const float* b1 = (const float*)d_in[3];
    const float* W2 = (const float*)d_in[4];
    const float* b2 = (const float*)d_in[5];
    const float* W3 = (const float*)d_in[6];
    const float* b3 = (const float*)d_in[7];
    float* out = (float*)d_out;

    dim3 grid(NB * NB), block(NT);
    gnn_fused<<<grid, block, 0, stream>>>(x, W1, b1, W2, b2, W3, b3, out);
}